// Round 3
// baseline (320.468 us; speedup 1.0000x reference)
//
#include <hip/hip_runtime.h>
#include <math.h>

static constexpr int Bq  = 8;
static constexpr int DIN = 1024;
static constexpr int TTT = 2048;
static constexpr int KCB = 8192;

static constexpr int NCHA = 8;     // approx chunks (MFMA)
static constexpr int CPCA = 1024;  // codes per approx chunk
static constexpr float E_BOUND = 2.5e-4f;  // >= 19x the analyzed approx error

// d_out layout (floats)
static constexpr size_t OUT_OFS  = 0;
static constexpr size_t LOSS_OFS = (size_t)Bq * DIN * TTT;      // 16777216 (16 zeros)
static constexpr size_t IDX_OFS  = LOSS_OFS + 16;               // 16777232 (B*T)
static constexpr size_t ZE_OFS   = IDX_OFS + (size_t)Bq * TTT;  // 16793616 (B*8*T)

// ws layout (float offsets)
static constexpr size_t WS_CBN   = 0;          // 8192*8 normalized codebook (fp32, exact path)
static constexpr size_t WS_C2    = 65536;      // 8192 0.5*||c_n||^2 (exact path)
static constexpr size_t WS_WT    = 73728;      // 1024*8 transposed w_in
static constexpr size_t WS_ENC   = 81920;      // 16384*8 z_e row-major [row][cd]
static constexpr size_t WS_FRAGH = 212992;     // bf16-hi fragments, ushort[8192*16] (fragment order)
static constexpr size_t WS_FRAGL = 278528;     // bf16-lo fragments
static constexpr size_t WS_PART  = 344064;     // float[NCHA][16384] approx chunk-min scores
static constexpr size_t WS_IDXI  = WS_PART + (size_t)NCHA * 16384; // 16384 ints

typedef __attribute__((ext_vector_type(8)))  short bf16x8;
typedef __attribute__((ext_vector_type(16))) float f32x16;

__device__ __forceinline__ unsigned short bf16_rn(float x) {
  unsigned u = __float_as_uint(x);
  unsigned r = (u + 0x7FFFu + ((u >> 16) & 1u)) >> 16;
  return (unsigned short)r;
}
__device__ __forceinline__ float bf16_to_f(unsigned short h) {
  return __uint_as_float(((unsigned)h) << 16);
}

// Shared helpers: the bit-identical fp32 DAG for the EXACT path (k2b).
__device__ __forceinline__ void load_enc_neg_norm(const float* __restrict__ ws,
                                                  int r, float4& ma, float4& mb) {
  const float4* ep = (const float4*)(ws + WS_ENC + (size_t)r * 8);
  float4 a = ep[0], c = ep[1];
  float n2 = 0.f;
  n2 = fmaf(a.x, a.x, n2); n2 = fmaf(a.y, a.y, n2);
  n2 = fmaf(a.z, a.z, n2); n2 = fmaf(a.w, a.w, n2);
  n2 = fmaf(c.x, c.x, n2); n2 = fmaf(c.y, c.y, n2);
  n2 = fmaf(c.z, c.z, n2); n2 = fmaf(c.w, c.w, n2);
  float dn = fmaxf(sqrtf(n2), 1e-12f);
  ma.x = -(a.x / dn); ma.y = -(a.y / dn);
  ma.z = -(a.z / dn); ma.w = -(a.w / dn);
  mb.x = -(c.x / dn); mb.y = -(c.y / dn);
  mb.z = -(c.z / dn); mb.w = -(c.w / dn);
}

__device__ __forceinline__ float score8(const float4& ma, const float4& mb,
                                        const float4& c0, const float4& c1, float cc) {
  // score = 0.5*||c_n||^2 - enc_n . c_n (monotone transform of reference dist)
  float s = fmaf(ma.x, c0.x, cc);
  s = fmaf(ma.y, c0.y, s); s = fmaf(ma.z, c0.z, s); s = fmaf(ma.w, c0.w, s);
  s = fmaf(mb.x, c1.x, s); s = fmaf(mb.y, c1.y, s);
  s = fmaf(mb.z, c1.z, s); s = fmaf(mb.w, c1.w, s);
  return s;
}

// Exact rescan of a 128-code slice; first-min via strict < with ascending k.
__device__ __forceinline__ void scan_slice(const float* __restrict__ ws, int base,
                                           const float4& ma, const float4& mb,
                                           float& best, int& bi) {
#pragma unroll 4
  for (int k = 0; k < 128; k++) {
    const float4* cp = (const float4*)(ws + WS_CBN + (size_t)(base + k) * 8);
    float4 c0 = cp[0], c1 = cp[1];
    float cc = ws[WS_C2 + base + k];
    float s = score8(ma, mb, c0, c1, cc);
    if (s < best) { best = s; bi = base + k; }
  }
}

// ---------------- K0: normalize codebook, build bf16-split MFMA fragments,
// transpose w_in, zero losses ----------
__global__ __launch_bounds__(256) void k0_prep(
    const float* __restrict__ w_in, const float* __restrict__ codebook,
    float* __restrict__ ws, float* __restrict__ out)
{
  int tid = blockIdx.x * 256 + threadIdx.x;
  if (tid < KCB) {
    const float4* cp = (const float4*)(codebook + (size_t)tid * 8);
    float4 a = cp[0], b = cp[1];
    float v[8] = {a.x, a.y, a.z, a.w, b.x, b.y, b.z, b.w};
    float n2 = 0.f;
#pragma unroll
    for (int o = 0; o < 8; o++) n2 = fmaf(v[o], v[o], n2);
    float dn = fmaxf(sqrtf(n2), 1e-12f);
    float u[8];
    float s2 = 0.f;
#pragma unroll
    for (int o = 0; o < 8; o++) { u[o] = v[o] / dn; s2 = fmaf(u[o], u[o], s2); }
    float4* wp = (float4*)(ws + WS_CBN + (size_t)tid * 8);
    wp[0] = make_float4(u[0], u[1], u[2], u[3]);
    wp[1] = make_float4(u[4], u[5], u[6], u[7]);
    float cc = 0.5f * s2;
    ws[WS_C2 + tid] = cc;  // folded half-norm for score = 0.5*c2 - dot

    // MFMA fragments: 16 K-lanes per code. k=0..7: split(c_n); k=8: split(-cc); k>8: 0.
    unsigned short h[16], l[16];
#pragma unroll
    for (int o = 0; o < 16; o++) { h[o] = 0; l[o] = 0; }
#pragma unroll
    for (int o = 0; o < 8; o++) {
      unsigned short hh = bf16_rn(u[o]);
      h[o] = hh;
      l[o] = bf16_rn(u[o] - bf16_to_f(hh));
    }
    {
      unsigned short hh = bf16_rn(-cc);
      h[8] = hh;
      l[8] = bf16_rn(-cc - bf16_to_f(hh));
    }
    // fragment-order store for mfma_32x32x16: B-lane = (col) or (col+32) for k-half,
    // 8 ushort per lane. Tile = 32 codes, chunk = 32 tiles (1024 codes).
    int cgrp = tid >> 10;        // approx chunk
    int tl   = (tid >> 5) & 31;  // tile within chunk
    int lcol = tid & 31;         // column within tile
    size_t fb = (size_t)cgrp * 16384 + (size_t)tl * 512;  // ushort units
    unsigned short* FH = (unsigned short*)(ws + WS_FRAGH);
    unsigned short* FL = (unsigned short*)(ws + WS_FRAGL);
#pragma unroll
    for (int e = 0; e < 8; e++) {
      FH[fb + (size_t)lcol * 8 + e]        = h[e];
      FH[fb + (size_t)(lcol + 32) * 8 + e] = h[8 + e];
      FL[fb + (size_t)lcol * 8 + e]        = l[e];
      FL[fb + (size_t)(lcol + 32) * 8 + e] = l[8 + e];
    }
  } else if (tid < KCB + DIN) {
    int d = tid - KCB;
#pragma unroll
    for (int o = 0; o < 8; o++) ws[WS_WT + (size_t)d * 8 + o] = w_in[(size_t)o * DIN + d];
  } else if (tid < KCB + DIN + 16) {
    out[LOSS_OFS + (tid - KCB - DIN)] = 0.f;  // commit_loss + codebook_loss zeros
  }
}

// ---------------- K1: z_e = w_in @ z + b_in  (HBM-bound, 64 MiB read) ----------
__global__ __launch_bounds__(512) void k1_proj_in(
    const float* __restrict__ z, const float* __restrict__ b_in,
    float* __restrict__ ws, float* __restrict__ out)
{
  __shared__ __align__(16) float lds[16384];  // 64 KB: wt staging, then partial[32][8][64]
  int tid = threadIdx.x;
  int bx = blockIdx.x;
  int b = bx >> 5;
  int t0 = (bx & 31) << 6;
  {
    const float4* src = (const float4*)(ws + WS_WT);
    float4* dst = (float4*)lds;
#pragma unroll
    for (int i = 0; i < 4; i++) dst[tid + 512 * i] = src[tid + 512 * i];
  }
  __syncthreads();
  int tt = tid & 15;
  int dg = tid >> 4;
  const float* zb = z + (size_t)b * DIN * TTT + t0 + (tt << 2);
  float4 acc[8];
#pragma unroll
  for (int o = 0; o < 8; o++) acc[o] = make_float4(0.f, 0.f, 0.f, 0.f);
  int dbase = dg << 5;
  const float4* wl = (const float4*)lds;
#pragma unroll 8
  for (int i = 0; i < 32; i++) {
    int d = dbase + i;
    float4 zv = *(const float4*)(zb + (size_t)d * TTT);
    float4 w0 = wl[d * 2 + 0];
    float4 w1 = wl[d * 2 + 1];
#define ACC1(o, wsc)                                    \
    acc[o].x = fmaf(wsc, zv.x, acc[o].x);               \
    acc[o].y = fmaf(wsc, zv.y, acc[o].y);               \
    acc[o].z = fmaf(wsc, zv.z, acc[o].z);               \
    acc[o].w = fmaf(wsc, zv.w, acc[o].w);
    ACC1(0, w0.x) ACC1(1, w0.y) ACC1(2, w0.z) ACC1(3, w0.w)
    ACC1(4, w1.x) ACC1(5, w1.y) ACC1(6, w1.z) ACC1(7, w1.w)
#undef ACC1
  }
  __syncthreads();
  {
    float4* pl = (float4*)lds;
#pragma unroll
    for (int o = 0; o < 8; o++) pl[dg * 128 + o * 16 + tt] = acc[o];
  }
  __syncthreads();
  int o = tid >> 6;
  int t = tid & 63;
  float s = 0.f;
#pragma unroll
  for (int g = 0; g < 32; g++) s += lds[g * 512 + o * 64 + t];
  s += b_in[o];
  out[ZE_OFS + ((size_t)b * 8 + o) * TTT + t0 + t] = s;
  ws[WS_ENC + ((size_t)(b * TTT + t0 + t)) * 8 + o] = s;
}

// ---------------- K2: approx VQ min-scan on the MFMA pipe.
// grid 1024 = rowgroups(128, 128 rows each) x chunks(8, 1024 codes each).
// block 256 = 4 waves; each wave owns 32 rows. Codebook chunk staged in LDS in
// fragment order (hi+lo bf16). Per 32-code tile: 3x mfma_f32_32x32x16_bf16
// (eh*ch, eh*cl, el*ch) into one fp32 acc; K-lane 8 folds -0.5*||c||^2 via
// A-pad=1.0, B-pad=split(-cc). Per-row chunk-min = -max(acc) after a cross-lane
// max butterfly. Approx error <= ~1.3e-5 << E_BOUND; k2b makes the final
// argmin exact regardless.
__global__ __launch_bounds__(256) void k2_scan(float* __restrict__ ws)
{
  __shared__ __align__(16) unsigned short lh[16384];  // 32 KB hi fragments
  __shared__ __align__(16) unsigned short ll[16384];  // 32 KB lo fragments
  int tid = threadIdx.x;
  int rg = blockIdx.x >> 3;  // 128 rowgroups of 128 rows
  int ch = blockIdx.x & 7;   // 8 chunks of 1024 codes
  {
    const float4* srcH = (const float4*)(ws + WS_FRAGH) + (size_t)ch * 2048;
    const float4* srcL = (const float4*)(ws + WS_FRAGL) + (size_t)ch * 2048;
    float4* dH = (float4*)lh;
    float4* dL = (float4*)ll;
#pragma unroll
    for (int i = 0; i < 8; i++) {
      dH[tid + 256 * i] = srcH[tid + 256 * i];
      dL[tid + 256 * i] = srcL[tid + 256 * i];
    }
  }
  int lane = tid & 63;
  int wv = tid >> 6;
  int rowbase = rg * 128 + wv * 32;
  int row = rowbase + (lane & 31);

  // A fragments: lanes 0-31 carry k=0..7 = normalized enc; lanes 32-63 carry
  // k=8..15 = [1.0, 0 x7] (the cc-fold lane).
  bf16x8 eh, el;
#pragma unroll
  for (int o = 0; o < 8; o++) { eh[o] = 0; el[o] = 0; }
  {
    const float4* ep = (const float4*)(ws + WS_ENC + (size_t)row * 8);
    float4 a = ep[0], c = ep[1];
    float n2 = 0.f;
    n2 = fmaf(a.x, a.x, n2); n2 = fmaf(a.y, a.y, n2);
    n2 = fmaf(a.z, a.z, n2); n2 = fmaf(a.w, a.w, n2);
    n2 = fmaf(c.x, c.x, n2); n2 = fmaf(c.y, c.y, n2);
    n2 = fmaf(c.z, c.z, n2); n2 = fmaf(c.w, c.w, n2);
    float dn = fmaxf(sqrtf(n2), 1e-12f);
    float v[8] = {a.x / dn, a.y / dn, a.z / dn, a.w / dn,
                  c.x / dn, c.y / dn, c.z / dn, c.w / dn};
    if (lane < 32) {
#pragma unroll
      for (int o = 0; o < 8; o++) {
        unsigned short hh = bf16_rn(v[o]);
        eh[o] = (short)hh;
        el[o] = (short)bf16_rn(v[o] - bf16_to_f(hh));
      }
    } else {
      eh[0] = (short)0x3F80;  // 1.0 in bf16
    }
  }
  __syncthreads();

  f32x16 rmax;
#pragma unroll
  for (int i = 0; i < 16; i++) rmax[i] = -3.4e38f;

  for (int t2 = 0; t2 < 32; t2 += 2) {
    bf16x8 bh0 = *(const bf16x8*)(&lh[((size_t)t2 * 64 + lane) * 8]);
    bf16x8 bl0 = *(const bf16x8*)(&ll[((size_t)t2 * 64 + lane) * 8]);
    bf16x8 bh1 = *(const bf16x8*)(&lh[((size_t)(t2 + 1) * 64 + lane) * 8]);
    bf16x8 bl1 = *(const bf16x8*)(&ll[((size_t)(t2 + 1) * 64 + lane) * 8]);
    f32x16 accA, accB;
#pragma unroll
    for (int i = 0; i < 16; i++) { accA[i] = 0.f; accB[i] = 0.f; }
    accA = __builtin_amdgcn_mfma_f32_32x32x16_bf16(eh, bh0, accA, 0, 0, 0);
    accA = __builtin_amdgcn_mfma_f32_32x32x16_bf16(eh, bl0, accA, 0, 0, 0);
    accA = __builtin_amdgcn_mfma_f32_32x32x16_bf16(el, bh0, accA, 0, 0, 0);
    accB = __builtin_amdgcn_mfma_f32_32x32x16_bf16(eh, bh1, accB, 0, 0, 0);
    accB = __builtin_amdgcn_mfma_f32_32x32x16_bf16(eh, bl1, accB, 0, 0, 0);
    accB = __builtin_amdgcn_mfma_f32_32x32x16_bf16(el, bh1, accB, 0, 0, 0);
#pragma unroll
    for (int i = 0; i < 16; i++) rmax[i] = fmaxf(fmaxf(rmax[i], accA[i]), accB[i]);
  }

  // cross-lane max over the 32 code-columns (stays within 32-lane halves)
#pragma unroll
  for (int off = 1; off <= 16; off <<= 1) {
#pragma unroll
    for (int i = 0; i < 16; i++) rmax[i] = fmaxf(rmax[i], __shfl_xor(rmax[i], off));
  }
  if ((lane & 31) == 0) {
    int rb2 = rowbase + 4 * (lane >> 5);
#pragma unroll
    for (int i = 0; i < 16; i++) {
      int rr = (i & 3) + 8 * (i >> 2);
      ws[WS_PART + (size_t)ch * 16384 + rb2 + rr] = -rmax[i];  // approx min score
    }
  }
}

// ---------------- K2b: EXACT argmin from approx chunk-mins.
// 8 threads/row. m~ = min approx; candidate chunks = approx <= m~ + 2E: provably
// contains the true-min chunk and all exact-tie chunks (E a valid bound).
// Candidates rescanned with the exact fp32 DAG in ascending chunk/code order ->
// reference first-min tie order. Post-check: if exact best > m~ + 2E (bound
// violated, e.g. wrong MFMA layout), fall back to full exact scan: always correct.
__global__ __launch_bounds__(256) void k2b_argmin(float* __restrict__ ws, float* __restrict__ out)
{
  int gtid = blockIdx.x * 256 + threadIdx.x;
  int r = gtid >> 3;
  int sub = gtid & 7;
  int lane = threadIdx.x & 63;
  float p = ws[WS_PART + (size_t)sub * 16384 + r];
  float m = p;
#pragma unroll
  for (int off = 1; off <= 4; off <<= 1) m = fminf(m, __shfl_xor(m, off));
  float thr = m + 2.0f * E_BOUND;

  float4 ma, mb;
  load_enc_neg_norm(ws, r, ma, mb);

  float best = 3.4e38f;
  int bi = 0x7fffffff;
  for (int ch = 0; ch < NCHA; ch++) {
    float pc = __shfl(p, (lane & 56) | ch);
    if (pc <= thr) {
      scan_slice(ws, (ch << 10) + (sub << 7), ma, mb, best, bi);
    }
  }
  float rbest = best;
  int rbi = bi;
#pragma unroll
  for (int off = 1; off <= 4; off <<= 1) {
    float os = __shfl_xor(rbest, off);
    int oi = __shfl_xor(rbi, off);
    if (os < rbest || (os == rbest && oi < rbi)) { rbest = os; rbi = oi; }
  }
  if (rbest > thr) {  // approx bound violated -> exact full scan (correct, slow)
    best = 3.4e38f; bi = 0x7fffffff;
    for (int ch = 0; ch < NCHA; ch++)
      scan_slice(ws, (ch << 10) + (sub << 7), ma, mb, best, bi);
    rbest = best; rbi = bi;
#pragma unroll
    for (int off = 1; off <= 4; off <<= 1) {
      float os = __shfl_xor(rbest, off);
      int oi = __shfl_xor(rbi, off);
      if (os < rbest || (os == rbest && oi < rbi)) { rbest = os; rbi = oi; }
    }
  }
  if (sub == 0) {
    out[IDX_OFS + r] = (float)rbi;
    ((int*)(ws + WS_IDXI))[r] = rbi;
  }
}

// ---------------- K3: out = w_out @ codebook[idx] + b_out (HBM write-bound) -----
__global__ __launch_bounds__(256) void k3_proj_out(
    const float* __restrict__ codebook, const float* __restrict__ w_out,
    const float* __restrict__ b_out, const float* __restrict__ ws,
    float* __restrict__ out)
{
  int bx = blockIdx.x;
  int b = bx >> 7;
  int th = (bx >> 6) & 1;
  int dt = bx & 63;
  int tid = threadIdx.x;
  int t = (th << 10) + (tid << 2);
  const int* idxp = (const int*)(ws + WS_IDXI);
  int4 id = *(const int4*)(idxp + b * TTT + t);
  const float4* cbp = (const float4*)codebook;
  float4 c00 = cbp[(size_t)id.x * 2], c01 = cbp[(size_t)id.x * 2 + 1];
  float4 c10 = cbp[(size_t)id.y * 2], c11 = cbp[(size_t)id.y * 2 + 1];
  float4 c20 = cbp[(size_t)id.z * 2], c21 = cbp[(size_t)id.z * 2 + 1];
  float4 c30 = cbp[(size_t)id.w * 2], c31 = cbp[(size_t)id.w * 2 + 1];
  int d0 = dt << 4;
#pragma unroll 4
  for (int dd = 0; dd < 16; dd++) {
    int d = d0 + dd;
    const float* wr = w_out + (size_t)d * 8;
    float w0 = wr[0], w1 = wr[1], w2 = wr[2], w3 = wr[3];
    float w4 = wr[4], w5 = wr[5], w6 = wr[6], w7 = wr[7];
    float bb = b_out[d];
#define DOT8(lo, hi)                                                          \
    fmaf(w7, hi.w, fmaf(w6, hi.z, fmaf(w5, hi.y, fmaf(w4, hi.x,              \
    fmaf(w3, lo.w, fmaf(w2, lo.z, fmaf(w1, lo.y, fmaf(w0, lo.x, bb))))))))
    float4 r;
    r.x = DOT8(c00, c01);
    r.y = DOT8(c10, c11);
    r.z = DOT8(c20, c21);
    r.w = DOT8(c30, c31);
#undef DOT8
    *(float4*)(out + OUT_OFS + ((size_t)b * DIN + d) * TTT + t) = r;
  }
}

extern "C" void kernel_launch(void* const* d_in, const int* in_sizes, int n_in,
                              void* d_out, int out_size, void* d_ws, size_t ws_size,
                              hipStream_t stream) {
  const float* z        = (const float*)d_in[0];
  const float* w_in     = (const float*)d_in[1];
  const float* b_in     = (const float*)d_in[2];
  const float* w_out    = (const float*)d_in[3];
  const float* b_out    = (const float*)d_in[4];
  const float* codebook = (const float*)d_in[5];
  float* out = (float*)d_out;
  float* ws  = (float*)d_ws;

  k0_prep<<<dim3(37), dim3(256), 0, stream>>>(w_in, codebook, ws, out);
  k1_proj_in<<<dim3(256), dim3(512), 0, stream>>>(z, b_in, ws, out);
  k2_scan<<<dim3(1024), dim3(256), 0, stream>>>(ws);
  k2b_argmin<<<dim3(512), dim3(256), 0, stream>>>(ws, out);
  k3_proj_out<<<dim3(1024), dim3(256), 0, stream>>>(codebook, w_out, b_out, ws, out);
}

// Round 4
// 188.260 us; speedup vs baseline: 1.7023x; 1.7023x over previous
//
#include <hip/hip_runtime.h>
#include <math.h>

static constexpr int Bq  = 8;
static constexpr int DIN = 1024;
static constexpr int TTT = 2048;
static constexpr int KCB = 8192;

static constexpr int NCHF = 32;    // fine chunks (candidate granularity)
static constexpr int CPCF = 256;   // codes per fine chunk
static constexpr float E_BOUND = 2.5e-4f;  // >= 6x the analyzed approx error

// d_out layout (floats)
static constexpr size_t OUT_OFS  = 0;
static constexpr size_t LOSS_OFS = (size_t)Bq * DIN * TTT;      // 16777216 (16 zeros)
static constexpr size_t IDX_OFS  = LOSS_OFS + 16;               // 16777232 (B*T)
static constexpr size_t ZE_OFS   = IDX_OFS + (size_t)Bq * TTT;  // 16793616 (B*8*T)

// ws layout (float offsets)
static constexpr size_t WS_CBN   = 0;          // 8192*8 normalized codebook (fp32, exact path)
static constexpr size_t WS_C2    = 65536;      // 8192 0.5*||c_n||^2 (exact path)
static constexpr size_t WS_WT    = 73728;      // 1024*8 transposed w_in
static constexpr size_t WS_ENC   = 81920;      // 16384*8 z_e row-major [row][cd]
static constexpr size_t WS_FRAGH = 212992;     // bf16-hi fragments, ushort[8192*16]
static constexpr size_t WS_FRAGL = 278528;     // bf16-lo fragments
static constexpr size_t WS_PART  = 344064;     // float[NCHF][16384] approx fine-chunk minima
static constexpr size_t WS_IDXI  = WS_PART + (size_t)NCHF * 16384; // 16384 ints

typedef __attribute__((ext_vector_type(8)))  short bf16x8;
typedef __attribute__((ext_vector_type(16))) float f32x16;

__device__ __forceinline__ unsigned short bf16_rn(float x) {
  unsigned u = __float_as_uint(x);
  unsigned r = (u + 0x7FFFu + ((u >> 16) & 1u)) >> 16;
  return (unsigned short)r;
}
__device__ __forceinline__ float bf16_to_f(unsigned short h) {
  return __uint_as_float(((unsigned)h) << 16);
}

// Shared helpers: the bit-identical fp32 DAG for the EXACT path (k2b).
__device__ __forceinline__ void load_enc_neg_norm(const float* __restrict__ ws,
                                                  int r, float4& ma, float4& mb) {
  const float4* ep = (const float4*)(ws + WS_ENC + (size_t)r * 8);
  float4 a = ep[0], c = ep[1];
  float n2 = 0.f;
  n2 = fmaf(a.x, a.x, n2); n2 = fmaf(a.y, a.y, n2);
  n2 = fmaf(a.z, a.z, n2); n2 = fmaf(a.w, a.w, n2);
  n2 = fmaf(c.x, c.x, n2); n2 = fmaf(c.y, c.y, n2);
  n2 = fmaf(c.z, c.z, n2); n2 = fmaf(c.w, c.w, n2);
  float dn = fmaxf(sqrtf(n2), 1e-12f);
  ma.x = -(a.x / dn); ma.y = -(a.y / dn);
  ma.z = -(a.z / dn); ma.w = -(a.w / dn);
  mb.x = -(c.x / dn); mb.y = -(c.y / dn);
  mb.z = -(c.z / dn); mb.w = -(c.w / dn);
}

__device__ __forceinline__ float score8(const float4& ma, const float4& mb,
                                        const float4& c0, const float4& c1, float cc) {
  // score = 0.5*||c_n||^2 - enc_n . c_n (monotone transform of reference dist)
  float s = fmaf(ma.x, c0.x, cc);
  s = fmaf(ma.y, c0.y, s); s = fmaf(ma.z, c0.z, s); s = fmaf(ma.w, c0.w, s);
  s = fmaf(mb.x, c1.x, s); s = fmaf(mb.y, c1.y, s);
  s = fmaf(mb.z, c1.z, s); s = fmaf(mb.w, c1.w, s);
  return s;
}

// Exact rescan of an 8-code slice; first-min via strict < with ascending k.
__device__ __forceinline__ void scan8(const float* __restrict__ ws, int base,
                                      const float4& ma, const float4& mb,
                                      float& best, int& bi) {
#pragma unroll
  for (int k = 0; k < 8; k++) {
    const float4* cp = (const float4*)(ws + WS_CBN + (size_t)(base + k) * 8);
    float4 c0 = cp[0], c1 = cp[1];
    float cc = ws[WS_C2 + base + k];
    float s = score8(ma, mb, c0, c1, cc);
    if (s < best) { best = s; bi = base + k; }
  }
}

// ---------------- K0: normalize codebook, build bf16-split MFMA fragments,
// transpose w_in, zero losses ----------
// Fragment layout for v_mfma_f32_32x32x16_bf16 B-operand (corrected, gfx950
// split-halves): lane l, elem j -> n = l&31, k = (l>>5)*4 + (j&3) + (j>>2)*8.
// Per code (col): lane c   (h=0): j0..3 = c_n dims 0..3, j4 = k8 = -cc, j5..7 = 0
//                 lane c+32(h=1): j0..3 = c_n dims 4..7, j4..7 = k12..15 = 0
__global__ __launch_bounds__(256) void k0_prep(
    const float* __restrict__ w_in, const float* __restrict__ codebook,
    float* __restrict__ ws, float* __restrict__ out)
{
  int tid = blockIdx.x * 256 + threadIdx.x;
  if (tid < KCB) {
    const float4* cp = (const float4*)(codebook + (size_t)tid * 8);
    float4 a = cp[0], b = cp[1];
    float v[8] = {a.x, a.y, a.z, a.w, b.x, b.y, b.z, b.w};
    float n2 = 0.f;
#pragma unroll
    for (int o = 0; o < 8; o++) n2 = fmaf(v[o], v[o], n2);
    float dn = fmaxf(sqrtf(n2), 1e-12f);
    float u[8];
    float s2 = 0.f;
#pragma unroll
    for (int o = 0; o < 8; o++) { u[o] = v[o] / dn; s2 = fmaf(u[o], u[o], s2); }
    float4* wp = (float4*)(ws + WS_CBN + (size_t)tid * 8);
    wp[0] = make_float4(u[0], u[1], u[2], u[3]);
    wp[1] = make_float4(u[4], u[5], u[6], u[7]);
    float cc = 0.5f * s2;
    ws[WS_C2 + tid] = cc;  // folded half-norm for score = 0.5*c2 - dot

    unsigned short h[8], l[8];
#pragma unroll
    for (int o = 0; o < 8; o++) {
      unsigned short hh = bf16_rn(u[o]);
      h[o] = hh;
      l[o] = bf16_rn(u[o] - bf16_to_f(hh));
    }
    unsigned short hcc = bf16_rn(-cc);
    unsigned short lcc = bf16_rn(-cc - bf16_to_f(hcc));

    int cgrp = tid >> 10;        // macro chunk (1024 codes)
    int tl   = (tid >> 5) & 31;  // tile within macro chunk
    int lcol = tid & 31;         // column within tile
    size_t fb = (size_t)cgrp * 16384 + (size_t)tl * 512;  // ushort units
    unsigned short* FH = (unsigned short*)(ws + WS_FRAGH);
    unsigned short* FL = (unsigned short*)(ws + WS_FRAGL);
    size_t p0 = fb + (size_t)lcol * 8;          // h=0 lane
    size_t p1 = fb + (size_t)(lcol + 32) * 8;   // h=1 lane
#pragma unroll
    for (int e = 0; e < 4; e++) {
      FH[p0 + e] = h[e];      FL[p0 + e] = l[e];
      FH[p1 + e] = h[4 + e];  FL[p1 + e] = l[4 + e];
      FH[p1 + 4 + e] = 0;     FL[p1 + 4 + e] = 0;
    }
    FH[p0 + 4] = hcc; FL[p0 + 4] = lcc;
    FH[p0 + 5] = 0; FH[p0 + 6] = 0; FH[p0 + 7] = 0;
    FL[p0 + 5] = 0; FL[p0 + 6] = 0; FL[p0 + 7] = 0;
  } else if (tid < KCB + DIN) {
    int d = tid - KCB;
#pragma unroll
    for (int o = 0; o < 8; o++) ws[WS_WT + (size_t)d * 8 + o] = w_in[(size_t)o * DIN + d];
  } else if (tid < KCB + DIN + 16) {
    out[LOSS_OFS + (tid - KCB - DIN)] = 0.f;  // commit_loss + codebook_loss zeros
  }
}

// ---------------- K1: z_e = w_in @ z + b_in  (HBM-bound, 64 MiB read) ----------
__global__ __launch_bounds__(512) void k1_proj_in(
    const float* __restrict__ z, const float* __restrict__ b_in,
    float* __restrict__ ws, float* __restrict__ out)
{
  __shared__ __align__(16) float lds[16384];  // 64 KB: wt staging, then partial[32][8][64]
  int tid = threadIdx.x;
  int bx = blockIdx.x;
  int b = bx >> 5;
  int t0 = (bx & 31) << 6;
  {
    const float4* src = (const float4*)(ws + WS_WT);
    float4* dst = (float4*)lds;
#pragma unroll
    for (int i = 0; i < 4; i++) dst[tid + 512 * i] = src[tid + 512 * i];
  }
  __syncthreads();
  int tt = tid & 15;
  int dg = tid >> 4;
  const float* zb = z + (size_t)b * DIN * TTT + t0 + (tt << 2);
  float4 acc[8];
#pragma unroll
  for (int o = 0; o < 8; o++) acc[o] = make_float4(0.f, 0.f, 0.f, 0.f);
  int dbase = dg << 5;
  const float4* wl = (const float4*)lds;
#pragma unroll 8
  for (int i = 0; i < 32; i++) {
    int d = dbase + i;
    float4 zv = *(const float4*)(zb + (size_t)d * TTT);
    float4 w0 = wl[d * 2 + 0];
    float4 w1 = wl[d * 2 + 1];
#define ACC1(o, wsc)                                    \
    acc[o].x = fmaf(wsc, zv.x, acc[o].x);               \
    acc[o].y = fmaf(wsc, zv.y, acc[o].y);               \
    acc[o].z = fmaf(wsc, zv.z, acc[o].z);               \
    acc[o].w = fmaf(wsc, zv.w, acc[o].w);
    ACC1(0, w0.x) ACC1(1, w0.y) ACC1(2, w0.z) ACC1(3, w0.w)
    ACC1(4, w1.x) ACC1(5, w1.y) ACC1(6, w1.z) ACC1(7, w1.w)
#undef ACC1
  }
  __syncthreads();
  {
    float4* pl = (float4*)lds;
#pragma unroll
    for (int o = 0; o < 8; o++) pl[dg * 128 + o * 16 + tt] = acc[o];
  }
  __syncthreads();
  int o = tid >> 6;
  int t = tid & 63;
  float s = 0.f;
#pragma unroll
  for (int g = 0; g < 32; g++) s += lds[g * 512 + o * 64 + t];
  s += b_in[o];
  out[ZE_OFS + ((size_t)b * 8 + o) * TTT + t0 + t] = s;
  ws[WS_ENC + ((size_t)(b * TTT + t0 + t)) * 8 + o] = s;
}

// ---------------- K2: approx VQ min-scan on the MFMA pipe.
// grid 1024 = rowgroups(128, 128 rows each) x macrochunks(8, 1024 codes each).
// block 256 = 4 waves; each wave owns 32 rows, no LDS (fragments stream from L2).
// Per 32-code tile: 3x mfma_f32_32x32x16_bf16 (eh*bh, eh*bl, el*bh) into fp32;
// k=8 folds -0.5*||c||^2 (A j4=1.0 on h=0 lanes, B j4=split(-cc)).
// Per-row minima stored per FINE chunk (256 codes = 8 tiles) = 4 per block.
// A-fragment layout (corrected): lane l elem j -> m=l&31, k=(l>>5)*4+(j&3)+(j>>2)*8.
__global__ __launch_bounds__(256) void k2_scan(float* __restrict__ ws)
{
  int tid = threadIdx.x;
  int rg = blockIdx.x >> 3;  // 128 rowgroups of 128 rows
  int ch = blockIdx.x & 7;   // 8 macro chunks of 1024 codes
  int lane = tid & 63;
  int wv = tid >> 6;
  int rowbase = rg * 128 + wv * 32;
  int row = rowbase + (lane & 31);
  int h = lane >> 5;

  bf16x8 eh, el;
#pragma unroll
  for (int o = 0; o < 8; o++) { eh[o] = 0; el[o] = 0; }
  {
    const float4* ep = (const float4*)(ws + WS_ENC + (size_t)row * 8);
    float4 a = ep[0], c = ep[1];
    float n2 = 0.f;
    n2 = fmaf(a.x, a.x, n2); n2 = fmaf(a.y, a.y, n2);
    n2 = fmaf(a.z, a.z, n2); n2 = fmaf(a.w, a.w, n2);
    n2 = fmaf(c.x, c.x, n2); n2 = fmaf(c.y, c.y, n2);
    n2 = fmaf(c.z, c.z, n2); n2 = fmaf(c.w, c.w, n2);
    float dn = fmaxf(sqrtf(n2), 1e-12f);
    float v[8] = {a.x / dn, a.y / dn, a.z / dn, a.w / dn,
                  c.x / dn, c.y / dn, c.z / dn, c.w / dn};
    int vb = h * 4;  // h=0 -> dims 0..3 (k 0..3); h=1 -> dims 4..7 (k 4..7)
#pragma unroll
    for (int o = 0; o < 4; o++) {
      unsigned short hh = bf16_rn(v[vb + o]);
      eh[o] = (short)hh;
      el[o] = (short)bf16_rn(v[vb + o] - bf16_to_f(hh));
    }
    if (h == 0) eh[4] = (short)0x3F80;  // A[m][k=8] = 1.0 (cc-fold lane)
  }

  const unsigned short* FH = (const unsigned short*)(ws + WS_FRAGH) + (size_t)ch * 16384;
  const unsigned short* FL = (const unsigned short*)(ws + WS_FRAGL) + (size_t)ch * 16384;

#pragma unroll
  for (int g = 0; g < 4; g++) {          // fine chunk = 8 tiles = 256 codes
    f32x16 rmax;
#pragma unroll
    for (int i = 0; i < 16; i++) rmax[i] = -3.4e38f;
#pragma unroll
    for (int p = 0; p < 4; p++) {        // 2 tiles per iter
      int t2 = g * 8 + p * 2;
      bf16x8 bh0 = *(const bf16x8*)(FH + ((size_t)t2 * 64 + lane) * 8);
      bf16x8 bl0 = *(const bf16x8*)(FL + ((size_t)t2 * 64 + lane) * 8);
      bf16x8 bh1 = *(const bf16x8*)(FH + ((size_t)(t2 + 1) * 64 + lane) * 8);
      bf16x8 bl1 = *(const bf16x8*)(FL + ((size_t)(t2 + 1) * 64 + lane) * 8);
      f32x16 accA, accB;
#pragma unroll
      for (int i = 0; i < 16; i++) { accA[i] = 0.f; accB[i] = 0.f; }
      accA = __builtin_amdgcn_mfma_f32_32x32x16_bf16(eh, bh0, accA, 0, 0, 0);
      accA = __builtin_amdgcn_mfma_f32_32x32x16_bf16(eh, bl0, accA, 0, 0, 0);
      accA = __builtin_amdgcn_mfma_f32_32x32x16_bf16(el, bh0, accA, 0, 0, 0);
      accB = __builtin_amdgcn_mfma_f32_32x32x16_bf16(eh, bh1, accB, 0, 0, 0);
      accB = __builtin_amdgcn_mfma_f32_32x32x16_bf16(eh, bl1, accB, 0, 0, 0);
      accB = __builtin_amdgcn_mfma_f32_32x32x16_bf16(el, bh1, accB, 0, 0, 0);
#pragma unroll
      for (int i = 0; i < 16; i++) rmax[i] = fmaxf(fmaxf(rmax[i], accA[i]), accB[i]);
    }
    // max over the 32 code-columns (butterfly within 32-lane halves)
#pragma unroll
    for (int off = 1; off <= 16; off <<= 1) {
#pragma unroll
      for (int i = 0; i < 16; i++) rmax[i] = fmaxf(rmax[i], __shfl_xor(rmax[i], off));
    }
    if ((lane & 31) == 0) {
      int rb2 = rowbase + 4 * h;  // C/D row = (i&3)+8*(i>>2)+4*(lane>>5)
      size_t pb = WS_PART + (size_t)(ch * 4 + g) * 16384 + rb2;
#pragma unroll
      for (int i = 0; i < 16; i++) {
        int rr = (i & 3) + 8 * (i >> 2);
        ws[pb + rr] = -rmax[i];  // approx fine-chunk min score
      }
    }
  }
}

// ---------------- K2b: EXACT argmin from approx fine-chunk minima.
// 32 threads/row (grid 2048x256). m~ = min over 32 approx minima; candidates =
// chunks with approx <= m~ + 2E (provably contains the true-min chunk and all
// exact ties when |approx-exact| <= E). Candidates rescanned in ascending
// chunk/code order with the exact fp32 DAG -> reference first-min tie order.
// Post-check: exact best > m~ + 2E (bound violated, e.g. wrong MFMA layout)
// -> full exact scan. Always correct; fast iff the approx path works.
__global__ __launch_bounds__(256) void k2b_argmin(float* __restrict__ ws, float* __restrict__ out)
{
  int gtid = blockIdx.x * 256 + threadIdx.x;
  int r = gtid >> 5;
  int sub = gtid & 31;
  int lane = threadIdx.x & 63;
  float p = ws[WS_PART + (size_t)sub * 16384 + r];
  float m = p;
#pragma unroll
  for (int off = 1; off <= 16; off <<= 1) m = fminf(m, __shfl_xor(m, off));
  float thr = m + 2.0f * E_BOUND;

  float4 ma, mb;
  load_enc_neg_norm(ws, r, ma, mb);

  float best = 3.4e38f;
  int bi = 0x7fffffff;
#pragma unroll 4
  for (int ch = 0; ch < NCHF; ch++) {
    float pc = __shfl(p, (lane & 32) | ch);
    if (pc <= thr) scan8(ws, (ch << 8) + (sub << 3), ma, mb, best, bi);
  }
  float rbest = best;
  int rbi = bi;
#pragma unroll
  for (int off = 1; off <= 16; off <<= 1) {
    float os = __shfl_xor(rbest, off);
    int oi = __shfl_xor(rbi, off);
    if (os < rbest || (os == rbest && oi < rbi)) { rbest = os; rbi = oi; }
  }
  if (rbest > thr) {  // approx bound violated -> exact full scan (correct, slow)
    best = 3.4e38f; bi = 0x7fffffff;
    for (int ch = 0; ch < NCHF; ch++)
      scan8(ws, (ch << 8) + (sub << 3), ma, mb, best, bi);
    rbest = best; rbi = bi;
#pragma unroll
    for (int off = 1; off <= 16; off <<= 1) {
      float os = __shfl_xor(rbest, off);
      int oi = __shfl_xor(rbi, off);
      if (os < rbest || (os == rbest && oi < rbi)) { rbest = os; rbi = oi; }
    }
  }
  if (sub == 0) {
    out[IDX_OFS + r] = (float)rbi;
    ((int*)(ws + WS_IDXI))[r] = rbi;
  }
}

// ---------------- K3: out = w_out @ codebook[idx] + b_out (HBM write-bound) -----
__global__ __launch_bounds__(256) void k3_proj_out(
    const float* __restrict__ codebook, const float* __restrict__ w_out,
    const float* __restrict__ b_out, const float* __restrict__ ws,
    float* __restrict__ out)
{
  int bx = blockIdx.x;
  int b = bx >> 7;
  int th = (bx >> 6) & 1;
  int dt = bx & 63;
  int tid = threadIdx.x;
  int t = (th << 10) + (tid << 2);
  const int* idxp = (const int*)(ws + WS_IDXI);
  int4 id = *(const int4*)(idxp + b * TTT + t);
  const float4* cbp = (const float4*)codebook;
  float4 c00 = cbp[(size_t)id.x * 2], c01 = cbp[(size_t)id.x * 2 + 1];
  float4 c10 = cbp[(size_t)id.y * 2], c11 = cbp[(size_t)id.y * 2 + 1];
  float4 c20 = cbp[(size_t)id.z * 2], c21 = cbp[(size_t)id.z * 2 + 1];
  float4 c30 = cbp[(size_t)id.w * 2], c31 = cbp[(size_t)id.w * 2 + 1];
  int d0 = dt << 4;
#pragma unroll 4
  for (int dd = 0; dd < 16; dd++) {
    int d = d0 + dd;
    const float* wr = w_out + (size_t)d * 8;
    float w0 = wr[0], w1 = wr[1], w2 = wr[2], w3 = wr[3];
    float w4 = wr[4], w5 = wr[5], w6 = wr[6], w7 = wr[7];
    float bb = b_out[d];
#define DOT8(lo, hi)                                                          \
    fmaf(w7, hi.w, fmaf(w6, hi.z, fmaf(w5, hi.y, fmaf(w4, hi.x,              \
    fmaf(w3, lo.w, fmaf(w2, lo.z, fmaf(w1, lo.y, fmaf(w0, lo.x, bb))))))))
    float4 r;
    r.x = DOT8(c00, c01);
    r.y = DOT8(c10, c11);
    r.z = DOT8(c20, c21);
    r.w = DOT8(c30, c31);
#undef DOT8
    *(float4*)(out + OUT_OFS + ((size_t)b * DIN + d) * TTT + t) = r;
  }
}

extern "C" void kernel_launch(void* const* d_in, const int* in_sizes, int n_in,
                              void* d_out, int out_size, void* d_ws, size_t ws_size,
                              hipStream_t stream) {
  const float* z        = (const float*)d_in[0];
  const float* w_in     = (const float*)d_in[1];
  const float* b_in     = (const float*)d_in[2];
  const float* w_out    = (const float*)d_in[3];
  const float* b_out    = (const float*)d_in[4];
  const float* codebook = (const float*)d_in[5];
  float* out = (float*)d_out;
  float* ws  = (float*)d_ws;

  k0_prep<<<dim3(37), dim3(256), 0, stream>>>(w_in, codebook, ws, out);
  k1_proj_in<<<dim3(256), dim3(512), 0, stream>>>(z, b_in, ws, out);
  k2_scan<<<dim3(1024), dim3(256), 0, stream>>>(ws);
  k2b_argmin<<<dim3(2048), dim3(256), 0, stream>>>(ws, out);
  k3_proj_out<<<dim3(1024), dim3(256), 0, stream>>>(codebook, w_out, b_out, ws, out);
}